// Round 3
// baseline (1149.025 us; speedup 1.0000x reference)
//
#include <hip/hip_runtime.h>

// ---------------------------------------------------------------------------
// VQ-VAE encoder + vector quantizer, fp32 end-to-end (no MFMA: argmin is a
// discrete decision; bf16 noise would flip indices vs the fp32 reference).
//
//   k_prep : eT[k][d] = emb[d][k];  c[k] = ||e_k||^2
//   k_conv1: 4x4 s2 SAME, 3->32, relu   (weights via wave-uniform s_loads)
//   k_conv2: 4x4 s2 SAME, 32->64, relu  (LDS-tiled implicit GEMM)
//   k_vq   : 1x1 conv 64->128 fused with argmin_k(c_k - 2 z.e_k) + gather
//
// Batch-chunked: the 64 images are processed in `nchunk` chunks so the h1/h2
// intermediates fit whatever ws_size the harness provides (worst case
// nchunk=64 needs ~3.4 MiB). Launch schedule is a pure function of ws_size
// -> identical work every call (graph-capture safe).
// ---------------------------------------------------------------------------

__device__ __forceinline__ float fget(const float4& v, int i) {
    return reinterpret_cast<const float*>(&v)[i];
}

// ---- K0: codebook prep --------------------------------------------------
__global__ void k_prep(const float* __restrict__ emb,
                       float* __restrict__ eT, float* __restrict__ cvec) {
    int k = blockIdx.x * 256 + threadIdx.x;   // 512 threads total
    float s = 0.f;
    #pragma unroll 8
    for (int d = 0; d < 128; ++d) {
        float v = emb[d * 512 + k];           // coalesced (consecutive k)
        s += v * v;
        eT[k * 128 + d] = v;
    }
    cvec[k] = s;
}

// ---- K1: conv1 + relu ---------------------------------------------------
// thread = one output pixel, all 32 channels. Weight indices are wave-uniform
// -> compiler emits s_load; weights live in SGPRs, FMAs take SGPR operand.
__global__ __launch_bounds__(256) void k_conv1(
        const float* __restrict__ x, const float* __restrict__ w1,
        const float* __restrict__ b1, float* __restrict__ h1, int b0) {
    int t = threadIdx.x;
    int p = blockIdx.x * 256 + t;             // chunk-local pixel id
    int ow = p & 127, oh = (p >> 7) & 127, b = b0 + (p >> 14);
    float acc[32];
    #pragma unroll
    for (int c = 0; c < 32; ++c) acc[c] = b1[c];     // uniform scalar loads
    #pragma unroll
    for (int kh = 0; kh < 4; ++kh) {
        int ih = oh * 2 - 1 + kh;                    // SAME pad_lo = 1
        if ((unsigned)ih >= 256u) continue;
        #pragma unroll
        for (int kw = 0; kw < 4; ++kw) {
            int iw = ow * 2 - 1 + kw;
            if ((unsigned)iw >= 256u) continue;
            const float* xp = x + (((size_t)(b * 256 + ih) * 256 + iw) * 3);
            float x0 = xp[0], x1 = xp[1], x2 = xp[2];
            const float* wp = w1 + (kh * 4 + kw) * 96;  // [ci][32c], uniform
            #pragma unroll
            for (int c = 0; c < 32; ++c)
                acc[c] += x0 * wp[c] + x1 * wp[32 + c] + x2 * wp[64 + c];
        }
    }
    float4* op = (float4*)(h1 + (size_t)p * 32);  // thread writes 1 cache line
    #pragma unroll
    for (int c4 = 0; c4 < 8; ++c4) {
        float4 v;
        v.x = fmaxf(acc[c4 * 4 + 0], 0.f);
        v.y = fmaxf(acc[c4 * 4 + 1], 0.f);
        v.z = fmaxf(acc[c4 * 4 + 2], 0.f);
        v.w = fmaxf(acc[c4 * 4 + 3], 0.f);
        op[c4] = v;
    }
}

// ---- K2: conv2 + relu (implicit GEMM, LDS-tiled) ------------------------
// block: 8x8 output pixels x 64 ch for one image. x-tile 18x18x32 in LDS
// (row padded to 580 floats -> 4-row stride = 2320 % 32 = 16 -> 2-way, free).
// weights staged per-kh (32KB). thread (tr,tc): tr->4 px (swizzled so in-wave
// groups differ in ROW), tc->4 cout. 64 FMA per 8 ds_read_b128.
#define XROW 580
__global__ __launch_bounds__(256) void k_conv2(
        const float* __restrict__ h1, const float* __restrict__ w2,
        const float* __restrict__ b2, float* __restrict__ h2) {
    __shared__ float xl[18 * XROW];     // 41.76 KB
    __shared__ float wl[8192];          // 32 KB  (one kh slice: [kw][ci][co])
    __shared__ float bl[64];
    int t = threadIdx.x;
    int blk = blockIdx.x;
    int tx = blk & 7, ty = (blk >> 3) & 7, b = blk >> 6;   // b = chunk-local
    int oh0 = ty * 8, ow0 = tx * 8;
    int ih0 = oh0 * 2 - 1, iw0 = ow0 * 2 - 1;
    if (t < 64) bl[t] = b2[t];
    // stage x tile: 18x18 positions x 8 float4 of channels
    for (int i = t; i < 2592; i += 256) {
        int f = i & 7;
        int pos = i >> 3;
        int r = pos / 18, c = pos - r * 18;
        int ih = ih0 + r, iw = iw0 + c;
        float4 v = make_float4(0.f, 0.f, 0.f, 0.f);
        if ((unsigned)ih < 128u && (unsigned)iw < 128u)
            v = *(const float4*)(h1 + ((size_t)((b * 128 + ih) * 128 + iw) * 32 + f * 4));
        *(float4*)(xl + r * XROW + c * 32 + f * 4) = v;
    }
    int tc = t & 15, tr = t >> 4;
    int g = ((tr & 3) << 2) | (tr >> 2);   // in-wave groups span different rows
    int olr = g >> 1, olc0 = (g & 1) * 4;
    __syncthreads();
    float4 bv = ((const float4*)bl)[tc];
    float4 acc[4];
    #pragma unroll
    for (int j = 0; j < 4; ++j) acc[j] = bv;
    for (int kh = 0; kh < 4; ++kh) {
        __syncthreads();                               // prev wl reads done
        const float4* wsrc = (const float4*)(w2 + kh * 8192);
        for (int i = t; i < 2048; i += 256) ((float4*)wl)[i] = wsrc[i];
        __syncthreads();
        #pragma unroll
        for (int kw = 0; kw < 4; ++kw) {
            #pragma unroll
            for (int ci4 = 0; ci4 < 8; ++ci4) {
                float4 xq[4], wq[4];
                #pragma unroll
                for (int j = 0; j < 4; ++j)
                    xq[j] = *(const float4*)(xl + (olr * 2 + kh) * XROW +
                                             ((olc0 + j) * 2 + kw) * 32 + ci4 * 4);
                #pragma unroll
                for (int i = 0; i < 4; ++i)
                    wq[i] = ((const float4*)wl)[(kw * 32 + ci4 * 4 + i) * 16 + tc];
                #pragma unroll
                for (int i = 0; i < 4; ++i) {
                    #pragma unroll
                    for (int j = 0; j < 4; ++j) {
                        float xv = fget(xq[j], i);
                        acc[j].x += xv * wq[i].x;
                        acc[j].y += xv * wq[i].y;
                        acc[j].z += xv * wq[i].z;
                        acc[j].w += xv * wq[i].w;
                    }
                }
            }
        }
    }
    int oh = oh0 + olr;
    #pragma unroll
    for (int j = 0; j < 4; ++j) {
        int ow = ow0 + olc0 + j;
        float4 v = acc[j];
        v.x = fmaxf(v.x, 0.f); v.y = fmaxf(v.y, 0.f);
        v.z = fmaxf(v.z, 0.f); v.w = fmaxf(v.w, 0.f);
        *(float4*)(h2 + ((size_t)((b * 64 + oh) * 64 + ow) * 64 + tc * 4)) = v;
    }
}

// ---- K3: conv3(1x1) + VQ argmin + gather, fused -------------------------
// block = 64 pixels. Phase A: z[64][128] into LDS (w3 staged in halves).
// Phase B: 8 chunks of 64 codes; thread (pr,kc) = 4 px x 4 codes register
// tile; running argmin of (c_k - 2 z.e_k)  (||z||^2 drops under argmin).
// Final: shfl_xor reduce over 16 lanes, coalesced gather from eT.
__global__ __launch_bounds__(256) void k_vq(
        const float* __restrict__ h2, const float* __restrict__ w3,
        const float* __restrict__ b3, const float* __restrict__ emb,
        const float* __restrict__ eT, const float* __restrict__ cvec,
        float* __restrict__ out, int px_base) {
    __shared__ float zl[64 * 132];   // 33.8 KB (row pad 132: 4px-stride -> 2-way)
    __shared__ float buf[8192];      // 32 KB union: {h2 tile + w3 half} / e-chunk
    __shared__ float cl[512];
    __shared__ float b3l[128];
    int t = threadIdx.x;
    size_t px0 = (size_t)blockIdx.x * 64;            // chunk-local
    {   // stage h2 tile -> buf[0..4095]
        const float4* src = (const float4*)(h2 + px0 * 64);
        for (int i = t; i < 1024; i += 256) ((float4*)buf)[i] = src[i];
    }
    if (t < 32) ((float4*)b3l)[t] = ((const float4*)b3)[t];
    if (t >= 128 && t < 256) ((float4*)cl)[t - 128] = ((const float4*)cvec)[t - 128];
    // ---- phase A: z = h2 @ w3 + b3, in d-halves (w3 half -> buf[4096..]) ----
    for (int dh = 0; dh < 2; ++dh) {
        __syncthreads();
        for (int i = t; i < 1024; i += 256) {
            int ci = i >> 4, dq = i & 15;
            ((float4*)buf)[1024 + i] =
                *(const float4*)(w3 + ci * 128 + dh * 64 + dq * 4);
        }
        __syncthreads();
        #pragma unroll
        for (int it = 0; it < 4; ++it) {
            int idx = t + it * 256;
            int px = idx >> 4, dq = idx & 15;
            float4 a = ((const float4*)b3l)[dh * 16 + dq];
            const float* hrow = buf + px * 64;
            const float4* wcol = ((const float4*)buf) + 1024;
            #pragma unroll 8
            for (int ci = 0; ci < 64; ++ci) {
                float hv = hrow[ci];
                float4 wv = wcol[ci * 16 + dq];
                a.x += hv * wv.x; a.y += hv * wv.y;
                a.z += hv * wv.z; a.w += hv * wv.w;
            }
            *(float4*)(zl + px * 132 + dh * 64 + dq * 4) = a;
        }
    }
    // ---- phase B: argmin over 512 codes in 8 chunks ----
    int kc = t & 15, pr = t >> 4;
    float minv[4]; int mini[4];
    #pragma unroll
    for (int j = 0; j < 4; ++j) { minv[j] = 3.4e38f; mini[j] = 0; }
    for (int kb = 0; kb < 8; ++kb) {
        __syncthreads();                    // prev buf readers done
        for (int i = t; i < 2048; i += 256) {
            int d = i >> 4, kq = i & 15;
            ((float4*)buf)[i] = *(const float4*)(emb + d * 512 + kb * 64 + kq * 4);
        }
        __syncthreads();
        float4 s[4];
        #pragma unroll
        for (int j = 0; j < 4; ++j) s[j] = make_float4(0.f, 0.f, 0.f, 0.f);
        #pragma unroll 4
        for (int d4 = 0; d4 < 32; ++d4) {
            float4 zq[4], eq[4];
            #pragma unroll
            for (int j = 0; j < 4; ++j)
                zq[j] = *(const float4*)(zl + (pr * 4 + j) * 132 + d4 * 4);
            #pragma unroll
            for (int i = 0; i < 4; ++i)
                eq[i] = ((const float4*)buf)[(d4 * 4 + i) * 16 + kc];
            #pragma unroll
            for (int i = 0; i < 4; ++i) {
                #pragma unroll
                for (int j = 0; j < 4; ++j) {
                    float zv = fget(zq[j], i);
                    s[j].x += zv * eq[i].x;
                    s[j].y += zv * eq[i].y;
                    s[j].z += zv * eq[i].z;
                    s[j].w += zv * eq[i].w;
                }
            }
        }
        int k0 = kb * 64 + kc * 4;
        #pragma unroll
        for (int j = 0; j < 4; ++j) {
            float d0 = cl[k0 + 0] - 2.f * s[j].x;
            float d1 = cl[k0 + 1] - 2.f * s[j].y;
            float d2 = cl[k0 + 2] - 2.f * s[j].z;
            float d3 = cl[k0 + 3] - 2.f * s[j].w;
            if (d0 < minv[j]) { minv[j] = d0; mini[j] = k0 + 0; }
            if (d1 < minv[j]) { minv[j] = d1; mini[j] = k0 + 1; }
            if (d2 < minv[j]) { minv[j] = d2; mini[j] = k0 + 2; }
            if (d3 < minv[j]) { minv[j] = d3; mini[j] = k0 + 3; }
        }
    }
    // ---- reduce over the 16 lanes sharing each pixel group; gather eT ----
    #pragma unroll
    for (int j = 0; j < 4; ++j) {
        float v = minv[j]; int ki = mini[j];
        #pragma unroll
        for (int off = 8; off > 0; off >>= 1) {
            float ov = __shfl_xor(v, off, 16);
            int oi = __shfl_xor(ki, off, 16);
            if (ov < v || (ov == v && oi < ki)) { v = ov; ki = oi; }
        }
        const float4* src = (const float4*)(eT + (size_t)ki * 128);
        float4* dst = (float4*)(out + ((size_t)px_base + px0 + pr * 4 + j) * 128);
        dst[kc] = src[kc];            // 16 lanes x 2 float4 = 128 floats
        dst[kc + 16] = src[kc + 16];
    }
}

// ---------------------------------------------------------------------------
extern "C" void kernel_launch(void* const* d_in, const int* in_sizes, int n_in,
                              void* d_out, int out_size, void* d_ws, size_t ws_size,
                              hipStream_t stream) {
    const float* x   = (const float*)d_in[0];
    const float* w1  = (const float*)d_in[1];
    const float* b1  = (const float*)d_in[2];
    const float* w2  = (const float*)d_in[3];
    const float* b2  = (const float*)d_in[4];
    const float* w3  = (const float*)d_in[5];
    const float* b3  = (const float*)d_in[6];
    const float* emb = (const float*)d_in[7];
    float* out = (float*)d_out;

    const size_t H1_FULL = 33554432;   // 64*128*128*32 floats (128 MiB)
    const size_t H2_FULL = 16777216;   // 64*64*64*64   floats ( 64 MiB)
    const size_t FIXEDF  = 65536 + 512;  // eT + cvec

    // smallest power-of-two chunk count whose peak scratch fits ws_size
    // (worst case nchunk=64 needs ~3.4 MiB; clamp there regardless)
    int nchunk = 1;
    while (nchunk < 64 &&
           (FIXEDF + (H1_FULL + H2_FULL) / (size_t)nchunk) * 4 > ws_size)
        nchunk <<= 1;
    int bpc = 64 / nchunk;             // images per chunk

    float* ws = (float*)d_ws;
    float* eT = ws;                    // 65,536 floats
    float* cv = eT + 65536;            // 512 floats
    float* h1 = cv + 512;              // H1_FULL/nchunk floats
    float* h2 = h1 + H1_FULL / (size_t)nchunk;  // H2_FULL/nchunk floats

    k_prep<<<2, 256, 0, stream>>>(emb, eT, cv);
    int nblk = 4096 / nchunk;          // blocks per chunk (>=64)
    for (int ch = 0; ch < nchunk; ++ch) {
        int b0 = ch * bpc;
        k_conv1<<<nblk, 256, 0, stream>>>(x, w1, b1, h1, b0);
        k_conv2<<<nblk, 256, 0, stream>>>(h1, w2, b2, h2);
        k_vq   <<<nblk, 256, 0, stream>>>(h2, w3, b3, emb, eT, cv, out,
                                          b0 * 4096);
    }
}